// Round 2
// baseline (813.688 us; speedup 1.0000x reference)
//
#include <hip/hip_runtime.h>
#include <hip/hip_bf16.h>

typedef __attribute__((ext_vector_type(8))) short short8;
typedef __attribute__((ext_vector_type(4))) float f32x4;

#define T_STEPS 48
#define BATCH 32
#define EDIM 512
#define HDIM 1024
#define VOCAB 32000

__device__ __forceinline__ unsigned short f2bf(float f) {
    __hip_bfloat16 h = __float2bfloat16(f);
    return *reinterpret_cast<unsigned short*>(&h);
}
__device__ __forceinline__ float bf2f(unsigned short u) {
    union { unsigned int i; float f; } v;
    v.i = ((unsigned int)u) << 16;
    return v.f;
}

// ---------------- prep: all fp32->bf16 conversions + embedding gather ----------------
__global__ __launch_bounds__(256) void prep_kernel(
    const float* __restrict__ h0, const int* __restrict__ tseq,
    const float* __restrict__ emb, const float* __restrict__ w_ih,
    const float* __restrict__ w_hh, const float* __restrict__ w_cls,
    unsigned short* __restrict__ wcls_bf, unsigned short* __restrict__ wih_bf,
    unsigned short* __restrict__ whh_hi, unsigned short* __restrict__ whh_lo,
    unsigned short* __restrict__ x_bf, unsigned short* __restrict__ hs_hi,
    unsigned short* __restrict__ hs_lo)
{
    const long R0 = (long)VOCAB * HDIM / 4;       // w_cls  (8,192,000)
    const long R1 = (long)3 * HDIM * EDIM / 4;    // w_ih   (393,216)
    const long R2 = (long)3 * HDIM * HDIM / 4;    // w_hh   (786,432) hi+lo
    const long R3 = (long)T_STEPS * BATCH * EDIM / 4; // X gather (196,608)
    const long R4 = (long)BATCH * HDIM / 4;       // h0 -> slot 0 hi+lo
    const long total = R0 + R1 + R2 + R3 + R4;

    for (long i = (long)blockIdx.x * blockDim.x + threadIdx.x; i < total;
         i += (long)gridDim.x * blockDim.x) {
        if (i < R0) {
            float4 v = reinterpret_cast<const float4*>(w_cls)[i];
            ushort4 u = { f2bf(v.x), f2bf(v.y), f2bf(v.z), f2bf(v.w) };
            *reinterpret_cast<ushort4*>(wcls_bf + i * 4) = u;
        } else if (i < R0 + R1) {
            long j = i - R0;
            float4 v = reinterpret_cast<const float4*>(w_ih)[j];
            ushort4 u = { f2bf(v.x), f2bf(v.y), f2bf(v.z), f2bf(v.w) };
            *reinterpret_cast<ushort4*>(wih_bf + j * 4) = u;
        } else if (i < R0 + R1 + R2) {
            long j = i - R0 - R1;
            float4 v = reinterpret_cast<const float4*>(w_hh)[j];
            ushort4 hi = { f2bf(v.x), f2bf(v.y), f2bf(v.z), f2bf(v.w) };
            ushort4 lo = { f2bf(v.x - bf2f(hi.x)), f2bf(v.y - bf2f(hi.y)),
                           f2bf(v.z - bf2f(hi.z)), f2bf(v.w - bf2f(hi.w)) };
            *reinterpret_cast<ushort4*>(whh_hi + j * 4) = hi;
            *reinterpret_cast<ushort4*>(whh_lo + j * 4) = lo;
        } else if (i < R0 + R1 + R2 + R3) {
            long j = i - R0 - R1 - R2;       // float4 item within X
            int m = (int)(j >> 7);           // row (t*32+b), 128 float4 per row
            int kk4 = (int)(j & 127);
            int t = m >> 5, b = m & 31;
            int tok = tseq[b * T_STEPS + t];
            float4 v = reinterpret_cast<const float4*>(emb)[(long)tok * (EDIM / 4) + kk4];
            ushort4 u = { f2bf(v.x), f2bf(v.y), f2bf(v.z), f2bf(v.w) };
            *reinterpret_cast<ushort4*>(x_bf + (long)m * EDIM + kk4 * 4) = u;
        } else {
            long j = i - R0 - R1 - R2 - R3;
            float4 v = reinterpret_cast<const float4*>(h0)[j];
            ushort4 hi = { f2bf(v.x), f2bf(v.y), f2bf(v.z), f2bf(v.w) };
            ushort4 lo = { f2bf(v.x - bf2f(hi.x)), f2bf(v.y - bf2f(hi.y)),
                           f2bf(v.z - bf2f(hi.z)), f2bf(v.w - bf2f(hi.w)) };
            *reinterpret_cast<ushort4*>(hs_hi + j * 4) = hi;   // slot 0
            *reinterpret_cast<ushort4*>(hs_lo + j * 4) = lo;
        }
    }
}

// ---------------- bf16 MFMA GEMM: C[M][Ntot](+bias) = A[M][K] * B[N][K]^T ----------------
// 128x128 tile, BK=32, 256 threads (4 waves, each owns a 64x64 quadrant).
template <bool SCORES>
__global__ __launch_bounds__(256) void gemm_bt(
    const unsigned short* __restrict__ A, const unsigned short* __restrict__ B,
    const float* __restrict__ bias, float* __restrict__ C, int K, int Ntot)
{
    const int n0 = blockIdx.x * 128;
    const int m0 = blockIdx.y * 128;
    const int tid = threadIdx.x;
    const int lane = tid & 63;
    const int wid = tid >> 6;
    const int wr = wid >> 1, wc = wid & 1;

    __shared__ __align__(16) unsigned short As[128 * 32];
    __shared__ __align__(16) unsigned short Bs[128 * 32];

    f32x4 acc[4][4] = {};
    short8 ra[2], rb[2];

    const int NT = K >> 5;

    // preload tile 0
    {
#pragma unroll
        for (int it = 0; it < 2; ++it) {
            int e = (tid + it * 256) * 8;
            int row = e >> 5, kk = e & 31;
            ra[it] = *(const short8*)(A + (size_t)(m0 + row) * K + kk);
            rb[it] = *(const short8*)(B + (size_t)(n0 + row) * K + kk);
        }
    }

    for (int kt = 0; kt < NT; ++kt) {
        __syncthreads();  // previous tile fully consumed
#pragma unroll
        for (int it = 0; it < 2; ++it) {
            int e = (tid + it * 256) * 8;
            *(short8*)(As + e) = ra[it];
            *(short8*)(Bs + e) = rb[it];
        }
        __syncthreads();
        if (kt + 1 < NT) {
            const int kbase = (kt + 1) * 32;
#pragma unroll
            for (int it = 0; it < 2; ++it) {
                int e = (tid + it * 256) * 8;
                int row = e >> 5, kk = e & 31;
                ra[it] = *(const short8*)(A + (size_t)(m0 + row) * K + kbase + kk);
                rb[it] = *(const short8*)(B + (size_t)(n0 + row) * K + kbase + kk);
            }
        }
        const int kg = lane >> 4;
        const int l15 = lane & 15;
        short8 af[4], bf[4];
#pragma unroll
        for (int i = 0; i < 4; ++i) {
            af[i] = *(const short8*)(As + ((wr * 64 + i * 16 + l15) * 32 + kg * 8));
            bf[i] = *(const short8*)(Bs + ((wc * 64 + i * 16 + l15) * 32 + kg * 8));
        }
#pragma unroll
        for (int i = 0; i < 4; ++i)
#pragma unroll
            for (int j = 0; j < 4; ++j)
                acc[i][j] = __builtin_amdgcn_mfma_f32_16x16x32_bf16(af[i], bf[j], acc[i][j], 0, 0, 0);
    }

    const int l15 = lane & 15, lhi = lane >> 4;
#pragma unroll
    for (int i = 0; i < 4; ++i) {
#pragma unroll
        for (int j = 0; j < 4; ++j) {
            int col = n0 + wc * 64 + j * 16 + l15;
            float bv = bias[col];
#pragma unroll
            for (int q = 0; q < 4; ++q) {
                int row = m0 + wr * 64 + i * 16 + lhi * 4 + q;
                float v = acc[i][j][q] + bv;
                if (SCORES) {
                    int t = row >> 5, b = row & 31;  // row = t*32+b
                    C[(size_t)(b * T_STEPS + t) * Ntot + col] = v;
                } else {
                    C[(size_t)row * Ntot + col] = v;
                }
            }
        }
    }
}

// ---------------- GRU step: gh = h @ W_hh^T (bf16x3), gates, h_new ----------------
// grid = 64 blocks; block owns 16 j's (all 3 gates) -> no cross-block dep inside a step.
// 4 waves split K=1024 into 256-chunks; LDS reduce; fp32 gates.
__global__ __launch_bounds__(256) void gru_step(
    unsigned short* __restrict__ hs_hi, unsigned short* __restrict__ hs_lo,
    const unsigned short* __restrict__ whh_hi, const unsigned short* __restrict__ whh_lo,
    const float* __restrict__ gi, const float* __restrict__ b_hh, int t)
{
    const int j0 = blockIdx.x * 16;
    const int tid = threadIdx.x;
    const int lane = tid & 63, wid = tid >> 6;
    const int l15 = lane & 15, kg = lane >> 4;

    const unsigned short* hA_hi = hs_hi + (size_t)t * BATCH * HDIM;
    const unsigned short* hA_lo = hs_lo + (size_t)t * BATCH * HDIM;

    __shared__ float P[4][32][48];

    f32x4 acc[2][3] = {};
    const int kq = wid * 256;
#pragma unroll
    for (int ks = 0; ks < 8; ++ks) {
        const int kb = kq + ks * 32 + kg * 8;
        short8 ahi[2], alo[2], bhi[3], blo[3];
#pragma unroll
        for (int mi = 0; mi < 2; ++mi) {
            const size_t off = (size_t)(mi * 16 + l15) * HDIM + kb;
            ahi[mi] = *(const short8*)(hA_hi + off);
            alo[mi] = *(const short8*)(hA_lo + off);
        }
#pragma unroll
        for (int g = 0; g < 3; ++g) {
            const size_t off = (size_t)(g * HDIM + j0 + l15) * HDIM + kb;
            bhi[g] = *(const short8*)(whh_hi + off);
            blo[g] = *(const short8*)(whh_lo + off);
        }
#pragma unroll
        for (int mi = 0; mi < 2; ++mi)
#pragma unroll
            for (int g = 0; g < 3; ++g) {
                acc[mi][g] = __builtin_amdgcn_mfma_f32_16x16x32_bf16(ahi[mi], bhi[g], acc[mi][g], 0, 0, 0);
                acc[mi][g] = __builtin_amdgcn_mfma_f32_16x16x32_bf16(ahi[mi], blo[g], acc[mi][g], 0, 0, 0);
                acc[mi][g] = __builtin_amdgcn_mfma_f32_16x16x32_bf16(alo[mi], bhi[g], acc[mi][g], 0, 0, 0);
            }
    }
    // scatter partials: C/D mapping col=lane&15, row=(lane>>4)*4+q
#pragma unroll
    for (int mi = 0; mi < 2; ++mi)
#pragma unroll
        for (int g = 0; g < 3; ++g)
#pragma unroll
            for (int q = 0; q < 4; ++q) {
                int b = mi * 16 + kg * 4 + q;
                int nn = g * 16 + l15;
                P[wid][b][nn] = acc[mi][g][q];
            }
    __syncthreads();

#pragma unroll
    for (int it = 0; it < 2; ++it) {
        int item = tid + it * 256;       // 512 items: 32 b x 16 jj
        int b = item >> 4, jj = item & 15;
        float ghr = 0.f, ghz = 0.f, ghn = 0.f;
#pragma unroll
        for (int w = 0; w < 4; ++w) {
            ghr += P[w][b][jj];
            ghz += P[w][b][16 + jj];
            ghn += P[w][b][32 + jj];
        }
        const int j = j0 + jj;
        ghr += b_hh[j];
        ghz += b_hh[HDIM + j];
        ghn += b_hh[2 * HDIM + j];
        const float* girow = gi + (size_t)(t * BATCH + b) * (3 * HDIM);
        float xr = girow[j], xz = girow[HDIM + j], xn = girow[2 * HDIM + j];
        float r = 1.f / (1.f + __expf(-(xr + ghr)));
        float z = 1.f / (1.f + __expf(-(xz + ghz)));
        float n = tanhf(xn + r * ghn);
        const size_t hoff = (size_t)b * HDIM + j;
        float hprev = bf2f(hA_hi[hoff]) + bf2f(hA_lo[hoff]);
        float hnew = (1.f - z) * n + z * hprev;
        unsigned short hi = f2bf(hnew);
        unsigned short lo = f2bf(hnew - bf2f(hi));
        const size_t o = (size_t)(t + 1) * BATCH * HDIM + hoff;
        hs_hi[o] = hi;
        hs_lo[o] = lo;
    }
}

extern "C" void kernel_launch(void* const* d_in, const int* in_sizes, int n_in,
                              void* d_out, int out_size, void* d_ws, size_t ws_size,
                              hipStream_t stream) {
    const float* h0    = (const float*)d_in[0];
    const int*   tseq  = (const int*)d_in[1];
    const float* emb   = (const float*)d_in[2];
    const float* w_ih  = (const float*)d_in[3];
    const float* w_hh  = (const float*)d_in[4];
    const float* b_ih  = (const float*)d_in[5];
    const float* b_hh  = (const float*)d_in[6];
    const float* w_cls = (const float*)d_in[7];
    const float* b_cls = (const float*)d_in[8];
    float* out = (float*)d_out;

    char* w = (char*)d_ws;
    unsigned short* wcls_bf = (unsigned short*)w; w += (size_t)VOCAB * HDIM * 2;
    unsigned short* wih_bf  = (unsigned short*)w; w += (size_t)3 * HDIM * EDIM * 2;
    unsigned short* whh_hi  = (unsigned short*)w; w += (size_t)3 * HDIM * HDIM * 2;
    unsigned short* whh_lo  = (unsigned short*)w; w += (size_t)3 * HDIM * HDIM * 2;
    unsigned short* x_bf    = (unsigned short*)w; w += (size_t)T_STEPS * BATCH * EDIM * 2;
    unsigned short* hs_hi   = (unsigned short*)w; w += (size_t)(T_STEPS + 1) * BATCH * HDIM * 2;
    unsigned short* hs_lo   = (unsigned short*)w; w += (size_t)(T_STEPS + 1) * BATCH * HDIM * 2;
    float* gi               = (float*)w;          w += (size_t)T_STEPS * BATCH * 3 * HDIM * 4;

    prep_kernel<<<2048, 256, 0, stream>>>(h0, tseq, emb, w_ih, w_hh, w_cls,
                                          wcls_bf, wih_bf, whh_hi, whh_lo,
                                          x_bf, hs_hi, hs_lo);

    // GI = X @ W_ih^T + b_ih : M=1536, N=3072, K=512
    gemm_bt<false><<<dim3(3 * HDIM / 128, T_STEPS * BATCH / 128), 256, 0, stream>>>(
        x_bf, wih_bf, b_ih, gi, EDIM, 3 * HDIM);

    for (int t = 0; t < T_STEPS; ++t)
        gru_step<<<64, 256, 0, stream>>>(hs_hi, hs_lo, whh_hi, whh_lo, gi, b_hh, t);

    // scores = Hs[1..48] @ W_cls^T + b_cls : M=1536, N=32000, K=1024, out [B][T][V]
    gemm_bt<true><<<dim3(VOCAB / 128, T_STEPS * BATCH / 128), 256, 0, stream>>>(
        hs_hi + (size_t)BATCH * HDIM, wcls_bf, b_cls, out, HDIM, VOCAB);
}